// Round 1
// baseline (1287.968 us; speedup 1.0000x reference)
//
#include <hip/hip_runtime.h>

#define BATCH 65536
#define NT 256

__device__ __forceinline__ float sigmoidf_(float x) { return 1.0f / (1.0f + __expf(-x)); }
__device__ __forceinline__ float tanhf_(float x) { return 2.0f / (1.0f + __expf(-2.0f * x)) - 1.0f; }

// ---------------- Kernel A1: conv1 (2x2, 3->16) + ReLU + maxpool2 ----------------
// obs: [B,7,7,3] NHWC. Output pooled_t: [144][B]  (feat = oc*9 + ph*3 + pw)
__global__ __launch_bounds__(NT) void k_conv1(const float* __restrict__ obs,
                                              const float* __restrict__ w1,
                                              const float* __restrict__ b1,
                                              float* __restrict__ pooled_t) {
  const int s = blockIdx.x * NT + threadIdx.x;
  const float* o = obs + (size_t)s * 147;
#pragma unroll 1
  for (int ph = 0; ph < 3; ++ph) {
    float r[3][21];
#pragma unroll
    for (int rr = 0; rr < 3; ++rr) {
      const float* orow = o + (2 * ph + rr) * 21;
#pragma unroll
      for (int i = 0; i < 21; ++i) r[rr][i] = orow[i];
    }
#pragma unroll 1
    for (int oc = 0; oc < 16; ++oc) {
      float wv[12];
#pragma unroll
      for (int i = 0; i < 12; ++i) wv[i] = w1[oc * 12 + i];  // [oc][c][kh][kw] -> c*4+kh*2+kw
      const float bias = b1[oc];
#pragma unroll
      for (int pw = 0; pw < 3; ++pw) {
        float m = 0.0f;  // relu(conv) >= 0, so 0 is a safe identity for the max
#pragma unroll
        for (int dh = 0; dh < 2; ++dh)
#pragma unroll
          for (int dw = 0; dw < 2; ++dw) {
            float acc = bias;
#pragma unroll
            for (int kh = 0; kh < 2; ++kh)
#pragma unroll
              for (int kw = 0; kw < 2; ++kw)
#pragma unroll
                for (int c = 0; c < 3; ++c)
                  acc += r[dh + kh][(2 * pw + dw + kw) * 3 + c] * wv[c * 4 + kh * 2 + kw];
            m = fmaxf(m, fmaxf(acc, 0.0f));
          }
        pooled_t[(size_t)(oc * 9 + ph * 3 + pw) * BATCH + s] = m;
      }
    }
  }
}

// ---------------- Kernel A2: conv2 (2x2, 16->32) + ReLU, conv3 (2x2, 32->64) + ReLU ----------------
// in pooled_t [144][B], out xt [64][B]
__global__ __launch_bounds__(NT) void k_conv23(const float* __restrict__ pooled_t,
                                               const float* __restrict__ w2,
                                               const float* __restrict__ b2,
                                               const float* __restrict__ w3,
                                               const float* __restrict__ b3,
                                               float* __restrict__ xt) {
  const int s = blockIdx.x * NT + threadIdx.x;
  float c2[128];  // [oc][oh*2+ow]
#pragma unroll
  for (int oc = 0; oc < 32; ++oc) {
    const float bb = b2[oc];
    c2[oc * 4 + 0] = bb; c2[oc * 4 + 1] = bb; c2[oc * 4 + 2] = bb; c2[oc * 4 + 3] = bb;
  }
#pragma unroll 1
  for (int ic = 0; ic < 16; ++ic) {
    float p9[9];
#pragma unroll
    for (int p = 0; p < 9; ++p) p9[p] = pooled_t[(size_t)(ic * 9 + p) * BATCH + s];
#pragma unroll
    for (int oc = 0; oc < 32; ++oc) {
      float w[4];
#pragma unroll
      for (int i = 0; i < 4; ++i) w[i] = w2[(oc * 16 + ic) * 4 + i];
#pragma unroll
      for (int oh = 0; oh < 2; ++oh)
#pragma unroll
        for (int ow = 0; ow < 2; ++ow)
          c2[oc * 4 + oh * 2 + ow] += p9[(oh + 0) * 3 + (ow + 0)] * w[0] +
                                      p9[(oh + 0) * 3 + (ow + 1)] * w[1] +
                                      p9[(oh + 1) * 3 + (ow + 0)] * w[2] +
                                      p9[(oh + 1) * 3 + (ow + 1)] * w[3];
    }
  }
#pragma unroll
  for (int i = 0; i < 128; ++i) c2[i] = fmaxf(c2[i], 0.0f);
#pragma unroll 1
  for (int oc = 0; oc < 64; ++oc) {
    float acc = b3[oc];
#pragma unroll
    for (int ic = 0; ic < 32; ++ic)
#pragma unroll
      for (int k = 0; k < 4; ++k) acc += c2[ic * 4 + k] * w3[(oc * 32 + ic) * 4 + k];
    xt[(size_t)oc * BATCH + s] = fmaxf(acc, 0.0f);
  }
}

// ---------------- Kernel B: 4 GRU cells + actor/critic heads ----------------
// out layout: [0,3B) log_probs, [3B,4B) value, [4B,4B+256B) memory_out
#define GRU_CELL(WIH, WHH, BIH, BHH, OFF)                                               \
  {                                                                                     \
    const float* hp = mem + (size_t)s * 256 + (OFF);                                    \
    float h[64];                                                                        \
    _Pragma("unroll") for (int k = 0; k < 16; ++k) {                                    \
      float4 v4 = *(const float4*)(hp + 4 * k);                                         \
      h[4 * k] = v4.x; h[4 * k + 1] = v4.y; h[4 * k + 2] = v4.z; h[4 * k + 3] = v4.w;   \
    }                                                                                   \
    _Pragma("unroll 1") for (int jj = 0; jj < 32; ++jj) {                               \
      float res0 = 0.0f, res1 = 0.0f;                                                   \
      _Pragma("unroll") for (int u = 0; u < 2; ++u) {                                   \
        const int j = jj * 2 + u;                                                       \
        float ir = (BIH)[j], iz = (BIH)[64 + j], inn = (BIH)[128 + j];                  \
        float hr = (BHH)[j], hz = (BHH)[64 + j], hnn = (BHH)[128 + j];                  \
        const float* wr = (WIH) + j * 64;                                               \
        const float* wz = (WIH) + (64 + j) * 64;                                        \
        const float* wn = (WIH) + (128 + j) * 64;                                       \
        const float* vr = (WHH) + j * 64;                                               \
        const float* vz = (WHH) + (64 + j) * 64;                                        \
        const float* vn = (WHH) + (128 + j) * 64;                                       \
        _Pragma("unroll") for (int k = 0; k < 64; ++k) {                                \
          ir += wr[k] * x[k]; iz += wz[k] * x[k]; inn += wn[k] * x[k];                  \
          hr += vr[k] * h[k]; hz += vz[k] * h[k]; hnn += vn[k] * h[k];                  \
        }                                                                               \
        const float rg = sigmoidf_(ir + hr);                                            \
        const float zg = sigmoidf_(iz + hz);                                            \
        const float ng = tanhf_(inn + rg * hnn);                                        \
        const float rv = (1.0f - zg) * ng + zg * hp[j];                                 \
        if (u == 0) res0 = rv; else res1 = rv;                                          \
      }                                                                                 \
      *(float2*)(omem + (OFF) + 2 * jj) = make_float2(res0, res1);                      \
    }                                                                                   \
    _Pragma("unroll") for (int k = 0; k < 16; ++k) {                                    \
      float4 v4 = *(const float4*)(omem + (OFF) + 4 * k);                               \
      x[4 * k] = v4.x; x[4 * k + 1] = v4.y; x[4 * k + 2] = v4.z; x[4 * k + 3] = v4.w;   \
    }                                                                                   \
  }

__global__ __launch_bounds__(NT) void k_gru(
    const float* __restrict__ xt, const float* __restrict__ mem,
    const float* __restrict__ wih0, const float* __restrict__ whh0,
    const float* __restrict__ bih0, const float* __restrict__ bhh0,
    const float* __restrict__ wih1, const float* __restrict__ whh1,
    const float* __restrict__ bih1, const float* __restrict__ bhh1,
    const float* __restrict__ wih2, const float* __restrict__ whh2,
    const float* __restrict__ bih2, const float* __restrict__ bhh2,
    const float* __restrict__ wih3, const float* __restrict__ whh3,
    const float* __restrict__ bih3, const float* __restrict__ bhh3,
    const float* __restrict__ aw1, const float* __restrict__ ab1,
    const float* __restrict__ aw2, const float* __restrict__ ab2,
    const float* __restrict__ cw1, const float* __restrict__ cb1,
    const float* __restrict__ cw2, const float* __restrict__ cb2,
    float* __restrict__ out) {
  const int s = blockIdx.x * NT + threadIdx.x;
  float x[64];
#pragma unroll
  for (int k = 0; k < 64; ++k) x[k] = xt[(size_t)k * BATCH + s];
  float* omem = out + (size_t)4 * BATCH + (size_t)s * 256;

  GRU_CELL(wih0, whh0, bih0, bhh0, 0)
  GRU_CELL(wih1, whh1, bih1, bhh1, 64)
  GRU_CELL(wih2, whh2, bih2, bhh2, 128)
  GRU_CELL(wih3, whh3, bih3, bhh3, 192)

  // x now holds the embedding (GRU2 top-layer output)
  float lg0 = ab2[0], lg1 = ab2[1], lg2 = ab2[2];
  float v = cb2[0];
#pragma unroll 1
  for (int j = 0; j < 64; ++j) {
    float a = ab1[j];
    float c = cb1[j];
#pragma unroll
    for (int k = 0; k < 64; ++k) {
      a += aw1[j * 64 + k] * x[k];
      c += cw1[j * 64 + k] * x[k];
    }
    a = fmaxf(a, 0.0f);
    c = fmaxf(c, 0.0f);
    lg0 += a * aw2[j];
    lg1 += a * aw2[64 + j];
    lg2 += a * aw2[128 + j];
    v += c * cw2[j];
  }
  const float m = fmaxf(lg0, fmaxf(lg1, lg2));
  const float e0 = __expf(lg0 - m), e1 = __expf(lg1 - m), e2 = __expf(lg2 - m);
  const float lse = m + __logf(e0 + e1 + e2);
  out[(size_t)s * 3 + 0] = lg0 - lse;
  out[(size_t)s * 3 + 1] = lg1 - lse;
  out[(size_t)s * 3 + 2] = lg2 - lse;
  out[(size_t)3 * BATCH + s] = v;
}

extern "C" void kernel_launch(void* const* d_in, const int* in_sizes, int n_in,
                              void* d_out, int out_size, void* d_ws, size_t ws_size,
                              hipStream_t stream) {
  (void)in_sizes; (void)n_in; (void)out_size; (void)ws_size;
  const float* obs = (const float*)d_in[0];
  const float* mem = (const float*)d_in[1];
  const float* w1 = (const float*)d_in[2];
  const float* b1 = (const float*)d_in[3];
  const float* w2 = (const float*)d_in[4];
  const float* b2 = (const float*)d_in[5];
  const float* w3 = (const float*)d_in[6];
  const float* b3 = (const float*)d_in[7];
  // g1 l0, g1 l1, g2 l0, g2 l1 : each (wih, whh, bih, bhh)
  const float* gw[16];
  for (int i = 0; i < 16; ++i) gw[i] = (const float*)d_in[8 + i];
  const float* aw1 = (const float*)d_in[24];
  const float* ab1 = (const float*)d_in[25];
  const float* aw2 = (const float*)d_in[26];
  const float* ab2 = (const float*)d_in[27];
  const float* cw1 = (const float*)d_in[28];
  const float* cb1 = (const float*)d_in[29];
  const float* cw2 = (const float*)d_in[30];
  const float* cb2 = (const float*)d_in[31];

  float* out = (float*)d_out;
  float* pooled_t = (float*)d_ws;                      // 144*B floats
  float* xt = pooled_t + (size_t)144 * BATCH;          // 64*B floats (total ws: 54.5MB)

  const dim3 grid(BATCH / NT), block(NT);
  hipLaunchKernelGGL(k_conv1, grid, block, 0, stream, obs, w1, b1, pooled_t);
  hipLaunchKernelGGL(k_conv23, grid, block, 0, stream, pooled_t, w2, b2, w3, b3, xt);
  hipLaunchKernelGGL(k_gru, grid, block, 0, stream, xt, mem,
                     gw[0], gw[1], gw[2], gw[3], gw[4], gw[5], gw[6], gw[7],
                     gw[8], gw[9], gw[10], gw[11], gw[12], gw[13], gw[14], gw[15],
                     aw1, ab1, aw2, ab2, cw1, cb1, cw2, cb2, out);
}

// Round 2
// 258.678 us; speedup vs baseline: 4.9790x; 4.9790x over previous
//
#include <hip/hip_runtime.h>

#define BATCH 65536
#define NT 256

typedef short bf16x8 __attribute__((ext_vector_type(8)));
typedef float f32x4 __attribute__((ext_vector_type(4)));
typedef unsigned short u16x8 __attribute__((ext_vector_type(8)));

__device__ __forceinline__ float sigmoidf_(float x) { return 1.0f / (1.0f + __expf(-x)); }
__device__ __forceinline__ float tanhf_(float x) { return 2.0f / (1.0f + __expf(-2.0f * x)) - 1.0f; }
__device__ __forceinline__ unsigned short f2b(float f) {
  union { float f; unsigned int u; } v; v.f = f;
  unsigned int r = (v.u + 0x7FFFu + ((v.u >> 16) & 1u)) >> 16;
  return (unsigned short)r;
}

// ---------------- prep: fp32 -> bf16 weight conversion ----------------
// wsW: 4 cells x [384][64]  (rows 0-191 = wih, rows 192-383 = whh)
// wsH: [128][64] (rows 0-63 = aw1, 64-127 = cw1)
__global__ __launch_bounds__(NT) void k_prep(
    const float* __restrict__ s0, const float* __restrict__ s1,
    const float* __restrict__ s2, const float* __restrict__ s3,
    const float* __restrict__ s4, const float* __restrict__ s5,
    const float* __restrict__ s6, const float* __restrict__ s7,
    const float* __restrict__ s8, const float* __restrict__ s9,
    unsigned short* __restrict__ wsW, unsigned short* __restrict__ wsH) {
  const int y = blockIdx.y;
  const float* src; unsigned short* dst; int n;
  if (y < 8) {
    n = 12288;
    const int c = y >> 1, p = y & 1;
    src = (y == 0) ? s0 : (y == 1) ? s1 : (y == 2) ? s2 : (y == 3) ? s3
        : (y == 4) ? s4 : (y == 5) ? s5 : (y == 6) ? s6 : s7;
    dst = wsW + c * 24576 + p * 12288;
  } else if (y == 8) { n = 4096; src = s8; dst = wsH; }
  else               { n = 4096; src = s9; dst = wsH + 4096; }
  const int i = blockIdx.x * NT + threadIdx.x;
  if (i < n) dst[i] = f2b(src[i]);
}

// ---------------- conv1 (2x2, 3->16) + ReLU + maxpool2, split by ph ----------------
__global__ __launch_bounds__(NT) void k_conv1(const float* __restrict__ obs,
                                              const float* __restrict__ w1,
                                              const float* __restrict__ b1,
                                              float* __restrict__ pooled_t) {
  const int ph = blockIdx.x >> 8;
  const int s = ((blockIdx.x & 255) << 8) + threadIdx.x;
  const float* o = obs + (size_t)s * 147;
  float r[3][21];
#pragma unroll
  for (int rr = 0; rr < 3; ++rr) {
    const float* orow = o + (2 * ph + rr) * 21;
#pragma unroll
    for (int i = 0; i < 21; ++i) r[rr][i] = orow[i];
  }
#pragma unroll 1
  for (int oc = 0; oc < 16; ++oc) {
    float wv[12];
#pragma unroll
    for (int i = 0; i < 12; ++i) wv[i] = w1[oc * 12 + i];
    const float bias = b1[oc];
#pragma unroll
    for (int pw = 0; pw < 3; ++pw) {
      float m = 0.0f;
#pragma unroll
      for (int dh = 0; dh < 2; ++dh)
#pragma unroll
        for (int dw = 0; dw < 2; ++dw) {
          float acc = bias;
#pragma unroll
          for (int kh = 0; kh < 2; ++kh)
#pragma unroll
            for (int kw = 0; kw < 2; ++kw)
#pragma unroll
              for (int c = 0; c < 3; ++c)
                acc += r[dh + kh][(2 * pw + dw + kw) * 3 + c] * wv[c * 4 + kh * 2 + kw];
          m = fmaxf(m, fmaxf(acc, 0.0f));
        }
      pooled_t[(size_t)(oc * 9 + ph * 3 + pw) * BATCH + s] = m;
    }
  }
}

// ---------------- conv2 (2x2, 16->32) + ReLU, split by oc half ----------------
__global__ __launch_bounds__(NT) void k_conv2(const float* __restrict__ pooled_t,
                                              const float* __restrict__ w2,
                                              const float* __restrict__ b2,
                                              float* __restrict__ c2t) {
  const int g = blockIdx.x >> 8;           // 0..1
  const int s = ((blockIdx.x & 255) << 8) + threadIdx.x;
  const int ocb = 16 * g;
  float acc[16][4];
#pragma unroll
  for (int u = 0; u < 16; ++u) {
    const float bb = b2[ocb + u];
    acc[u][0] = bb; acc[u][1] = bb; acc[u][2] = bb; acc[u][3] = bb;
  }
#pragma unroll 1
  for (int ic = 0; ic < 16; ++ic) {
    float p9[9];
#pragma unroll
    for (int p = 0; p < 9; ++p) p9[p] = pooled_t[(size_t)(ic * 9 + p) * BATCH + s];
#pragma unroll
    for (int u = 0; u < 16; ++u) {
      float w[4];
#pragma unroll
      for (int i = 0; i < 4; ++i) w[i] = w2[((ocb + u) * 16 + ic) * 4 + i];
#pragma unroll
      for (int oh = 0; oh < 2; ++oh)
#pragma unroll
        for (int ow = 0; ow < 2; ++ow)
          acc[u][oh * 2 + ow] += p9[(oh + 0) * 3 + (ow + 0)] * w[0] +
                                 p9[(oh + 0) * 3 + (ow + 1)] * w[1] +
                                 p9[(oh + 1) * 3 + (ow + 0)] * w[2] +
                                 p9[(oh + 1) * 3 + (ow + 1)] * w[3];
    }
  }
#pragma unroll
  for (int u = 0; u < 16; ++u)
#pragma unroll
    for (int p = 0; p < 4; ++p)
      c2t[(size_t)((ocb + u) * 4 + p) * BATCH + s] = fmaxf(acc[u][p], 0.0f);
}

// ---------------- conv3 (2x2, 32->64) + ReLU -> bf16 [B][64], split by oc half ----------------
__global__ __launch_bounds__(NT) void k_conv3(const float* __restrict__ c2t,
                                              const float* __restrict__ w3,
                                              const float* __restrict__ b3,
                                              unsigned short* __restrict__ xb) {
  const int g = blockIdx.x >> 8;           // 0..1
  const int s = ((blockIdx.x & 255) << 8) + threadIdx.x;
  const int ocb = 32 * g;
  float acc[32];
#pragma unroll
  for (int u = 0; u < 32; ++u) acc[u] = b3[ocb + u];
#pragma unroll 1
  for (int ic = 0; ic < 32; ++ic) {
    float c4[4];
#pragma unroll
    for (int k = 0; k < 4; ++k) c4[k] = c2t[(size_t)(ic * 4 + k) * BATCH + s];
#pragma unroll
    for (int u = 0; u < 32; ++u)
#pragma unroll
      for (int k = 0; k < 4; ++k)
        acc[u] += c4[k] * w3[((ocb + u) * 32 + ic) * 4 + k];
  }
  unsigned short ob[32];
#pragma unroll
  for (int u = 0; u < 32; ++u) ob[u] = f2b(fmaxf(acc[u], 0.0f));
#pragma unroll
  for (int i = 0; i < 4; ++i)
    *(u16x8*)(xb + (size_t)s * 64 + ocb + 8 * i) = *(const u16x8*)(ob + 8 * i);
}

// ---------------- GRU cell via MFMA ----------------
// Xin bf16 [B][64]; memF fp32 [B][256]; outMem fp32 [B][256] (memory_out region);
// Wb bf16 [384][64]; Xout bf16 [B][64]
__global__ __launch_bounds__(NT) void k_cell(const unsigned short* __restrict__ Xin,
                                             unsigned short* __restrict__ Xout,
                                             const float* __restrict__ memF,
                                             float* __restrict__ outMem,
                                             const unsigned short* __restrict__ Wb,
                                             const float* __restrict__ bih,
                                             const float* __restrict__ bhh,
                                             int cellOff) {
  const int lane = threadIdx.x & 63;
  const int wave = threadIdx.x >> 6;
  const int m_base = blockIdx.x * 64 + wave * 16;
  const int r16 = lane & 15;     // A-row (sample) for A-frags; D-col (gate j) for accs
  const int kg = lane >> 4;      // k-group

  // A fragments: X (bf16 direct) and H (fp32 -> bf16)
  bf16x8 ax[2], ah[2];
  {
    const unsigned short* xp = Xin + (size_t)(m_base + r16) * 64 + kg * 8;
    ax[0] = *(const bf16x8*)(xp);
    ax[1] = *(const bf16x8*)(xp + 32);
    const float* hp = memF + (size_t)(m_base + r16) * 256 + cellOff + kg * 8;
#pragma unroll
    for (int ks = 0; ks < 2; ++ks) {
      union { unsigned short u[8]; bf16x8 v; } t;
#pragma unroll
      for (int i = 0; i < 8; ++i) t.u[i] = f2b(hp[ks * 32 + i]);
      ah[ks] = t.v;
    }
  }

  f32x4 gi[12], gh[12];
#pragma unroll
  for (int n = 0; n < 12; ++n) { gi[n] = (f32x4)(0.0f); gh[n] = (f32x4)(0.0f); }

#pragma unroll
  for (int n = 0; n < 12; ++n) {
    const unsigned short* wg = Wb + (size_t)(n * 16 + r16) * 64 + kg * 8;
    const unsigned short* wh = Wb + (size_t)(192 + n * 16 + r16) * 64 + kg * 8;
    bf16x8 bg0 = *(const bf16x8*)(wg);
    bf16x8 bg1 = *(const bf16x8*)(wg + 32);
    bf16x8 bh0 = *(const bf16x8*)(wh);
    bf16x8 bh1 = *(const bf16x8*)(wh + 32);
    gi[n] = __builtin_amdgcn_mfma_f32_16x16x32_bf16(ax[0], bg0, gi[n], 0, 0, 0);
    gi[n] = __builtin_amdgcn_mfma_f32_16x16x32_bf16(ax[1], bg1, gi[n], 0, 0, 0);
    gh[n] = __builtin_amdgcn_mfma_f32_16x16x32_bf16(ah[0], bh0, gh[n], 0, 0, 0);
    gh[n] = __builtin_amdgcn_mfma_f32_16x16x32_bf16(ah[1], bh1, gh[n], 0, 0, 0);
  }

  // gate math: lane holds (sample = m_base + kg*4 + q, j = 16t + r16)
#pragma unroll
  for (int t = 0; t < 4; ++t) {
    const int j = 16 * t + r16;
    const float bihr = bih[j],       bhhr = bhh[j];
    const float bihz = bih[64 + j],  bhhz = bhh[64 + j];
    const float bihn = bih[128 + j], bhhn = bhh[128 + j];
#pragma unroll
    for (int q = 0; q < 4; ++q) {
      const int sq = m_base + kg * 4 + q;
      const float rg = sigmoidf_(gi[t][q] + bihr + gh[t][q] + bhhr);
      const float zg = sigmoidf_(gi[t + 4][q] + bihz + gh[t + 4][q] + bhhz);
      const float ng = tanhf_((gi[t + 8][q] + bihn) + rg * (gh[t + 8][q] + bhhn));
      const float ho = memF[(size_t)sq * 256 + cellOff + j];
      const float nh = (1.0f - zg) * ng + zg * ho;
      outMem[(size_t)sq * 256 + cellOff + j] = nh;
      Xout[(size_t)sq * 64 + j] = f2b(nh);
    }
  }
}

// ---------------- heads: relu(emb@[aw1;cw1]^T+b) then tiny 2nd layer + log_softmax ----------------
__global__ __launch_bounds__(NT) void k_heads(const unsigned short* __restrict__ emb,
                                              const unsigned short* __restrict__ wsH,
                                              const float* __restrict__ ab1,
                                              const float* __restrict__ cb1,
                                              const float* __restrict__ aw2,
                                              const float* __restrict__ ab2,
                                              const float* __restrict__ cw2,
                                              const float* __restrict__ cb2,
                                              float* __restrict__ out) {
  const int lane = threadIdx.x & 63;
  const int wave = threadIdx.x >> 6;
  const int m_base = blockIdx.x * 64 + wave * 16;
  const int r16 = lane & 15;
  const int kg = lane >> 4;

  bf16x8 ax[2];
  {
    const unsigned short* xp = emb + (size_t)(m_base + r16) * 64 + kg * 8;
    ax[0] = *(const bf16x8*)(xp);
    ax[1] = *(const bf16x8*)(xp + 32);
  }
  f32x4 acc[8];
#pragma unroll
  for (int n = 0; n < 8; ++n) acc[n] = (f32x4)(0.0f);
#pragma unroll
  for (int n = 0; n < 8; ++n) {
    const unsigned short* wp = wsH + (size_t)(n * 16 + r16) * 64 + kg * 8;
    bf16x8 b0 = *(const bf16x8*)(wp);
    bf16x8 b1 = *(const bf16x8*)(wp + 32);
    acc[n] = __builtin_amdgcn_mfma_f32_16x16x32_bf16(ax[0], b0, acc[n], 0, 0, 0);
    acc[n] = __builtin_amdgcn_mfma_f32_16x16x32_bf16(ax[1], b1, acc[n], 0, 0, 0);
  }
  // per-lane 2nd-layer weights (c = r16 is the j%16 slice)
  float w2a0[4], w2a1[4], w2a2[4], w2cc[4], ba[4], bc[4];
#pragma unroll
  for (int t = 0; t < 4; ++t) {
    const int j = 16 * t + r16;
    w2a0[t] = aw2[j]; w2a1[t] = aw2[64 + j]; w2a2[t] = aw2[128 + j];
    w2cc[t] = cw2[j]; ba[t] = ab1[j]; bc[t] = cb1[j];
  }
  const float b20 = ab2[0], b21 = ab2[1], b22 = ab2[2], b2c = cb2[0];
#pragma unroll
  for (int q = 0; q < 4; ++q) {
    float l0 = 0.0f, l1 = 0.0f, l2 = 0.0f, vv = 0.0f;
#pragma unroll
    for (int t = 0; t < 4; ++t) {
      const float av = fmaxf(acc[t][q] + ba[t], 0.0f);
      const float cv = fmaxf(acc[t + 4][q] + bc[t], 0.0f);
      l0 += av * w2a0[t]; l1 += av * w2a1[t]; l2 += av * w2a2[t];
      vv += cv * w2cc[t];
    }
#pragma unroll
    for (int m = 1; m < 16; m <<= 1) {
      l0 += __shfl_xor(l0, m); l1 += __shfl_xor(l1, m);
      l2 += __shfl_xor(l2, m); vv += __shfl_xor(vv, m);
    }
    if (r16 == 0) {
      const int sq = m_base + kg * 4 + q;
      const float g0 = l0 + b20, g1 = l1 + b21, g2 = l2 + b22;
      const float mx = fmaxf(g0, fmaxf(g1, g2));
      const float lse = mx + __logf(__expf(g0 - mx) + __expf(g1 - mx) + __expf(g2 - mx));
      out[(size_t)sq * 3 + 0] = g0 - lse;
      out[(size_t)sq * 3 + 1] = g1 - lse;
      out[(size_t)sq * 3 + 2] = g2 - lse;
      out[(size_t)3 * BATCH + sq] = vv + b2c;
    }
  }
}

extern "C" void kernel_launch(void* const* d_in, const int* in_sizes, int n_in,
                              void* d_out, int out_size, void* d_ws, size_t ws_size,
                              hipStream_t stream) {
  (void)in_sizes; (void)n_in; (void)out_size; (void)ws_size;
  const float* obs = (const float*)d_in[0];
  const float* mem = (const float*)d_in[1];
  const float* w1 = (const float*)d_in[2];
  const float* b1 = (const float*)d_in[3];
  const float* w2 = (const float*)d_in[4];
  const float* b2 = (const float*)d_in[5];
  const float* w3 = (const float*)d_in[6];
  const float* b3 = (const float*)d_in[7];
  const float* gw[16];
  for (int i = 0; i < 16; ++i) gw[i] = (const float*)d_in[8 + i];
  const float* aw1 = (const float*)d_in[24];
  const float* ab1 = (const float*)d_in[25];
  const float* aw2 = (const float*)d_in[26];
  const float* ab2 = (const float*)d_in[27];
  const float* cw1 = (const float*)d_in[28];
  const float* cb1 = (const float*)d_in[29];
  const float* cw2 = (const float*)d_in[30];
  const float* cb2 = (const float*)d_in[31];

  float* out = (float*)d_out;
  float* outMem = out + (size_t)4 * BATCH;

  char* w = (char*)d_ws;
  float* pooled_t = (float*)w;                                   // 144*B f32
  float* c2t = (float*)(w + (size_t)144 * BATCH * 4);            // 128*B f32
  unsigned short* xbA = (unsigned short*)(w + (size_t)272 * BATCH * 4);
  unsigned short* xbB = xbA + (size_t)64 * BATCH;
  unsigned short* wsW = xbB + (size_t)64 * BATCH;                // 4*384*64 bf16
  unsigned short* wsH = wsW + 98304;                             // 128*64 bf16

  const dim3 blk(NT);
  hipLaunchKernelGGL(k_prep, dim3(48, 10), blk, 0, stream,
                     gw[0], gw[1], gw[4], gw[5], gw[8], gw[9], gw[12], gw[13],
                     aw1, cw1, wsW, wsH);
  hipLaunchKernelGGL(k_conv1, dim3(768), blk, 0, stream, obs, w1, b1, pooled_t);
  hipLaunchKernelGGL(k_conv2, dim3(512), blk, 0, stream, pooled_t, w2, b2, c2t);
  hipLaunchKernelGGL(k_conv3, dim3(512), blk, 0, stream, c2t, w3, b3, xbA);

  hipLaunchKernelGGL(k_cell, dim3(BATCH / 64), blk, 0, stream,
                     xbA, xbB, mem, outMem, wsW + 0 * 24576, gw[2], gw[3], 0);
  hipLaunchKernelGGL(k_cell, dim3(BATCH / 64), blk, 0, stream,
                     xbB, xbA, mem, outMem, wsW + 1 * 24576, gw[6], gw[7], 64);
  hipLaunchKernelGGL(k_cell, dim3(BATCH / 64), blk, 0, stream,
                     xbA, xbB, mem, outMem, wsW + 2 * 24576, gw[10], gw[11], 128);
  hipLaunchKernelGGL(k_cell, dim3(BATCH / 64), blk, 0, stream,
                     xbB, xbA, mem, outMem, wsW + 3 * 24576, gw[14], gw[15], 192);

  hipLaunchKernelGGL(k_heads, dim3(BATCH / 64), blk, 0, stream,
                     xbA, wsH, ab1, cb1, aw2, ab2, cw2, cb2, out);
}

// Round 3
// 160.572 us; speedup vs baseline: 8.0211x; 1.6110x over previous
//
#include <hip/hip_runtime.h>

#define BATCH 65536
#define NT 256
#define MFMA __builtin_amdgcn_mfma_f32_16x16x32_bf16

typedef short bf16x8 __attribute__((ext_vector_type(8)));
typedef float f32x4 __attribute__((ext_vector_type(4)));
typedef unsigned short u16x8 __attribute__((ext_vector_type(8)));

__device__ __forceinline__ float sigmoidf_(float x) { return 1.0f / (1.0f + __expf(-x)); }
__device__ __forceinline__ float tanhf_(float x) { return 2.0f / (1.0f + __expf(-2.0f * x)) - 1.0f; }
__device__ __forceinline__ unsigned short f2b(float f) {
  union { float f; unsigned int u; } v; v.f = f;
  unsigned int r = (v.u + 0x7FFFu + ((v.u >> 16) & 1u)) >> 16;
  return (unsigned short)r;
}

// ---------------- prep: weights -> bf16, biases -> combined fp32 ----------------
// wsW: 4 cells x [384][64] (0-191 wih, 192-383 whh). wsH: [128][64] (aw1;cw1).
// wsW3: [64][128]. wsB: per cell [0,64)=bihr+bhhr [64,128)=bihz+bhhz [128,192)=bihn [192,256)=bhhn
__global__ __launch_bounds__(NT) void k_prep(
    const float* __restrict__ W0, const float* __restrict__ W1,
    const float* __restrict__ W2, const float* __restrict__ W3,
    const float* __restrict__ W4, const float* __restrict__ W5,
    const float* __restrict__ W6, const float* __restrict__ W7,
    const float* __restrict__ bi0, const float* __restrict__ bi1,
    const float* __restrict__ bi2, const float* __restrict__ bi3,
    const float* __restrict__ bh0, const float* __restrict__ bh1,
    const float* __restrict__ bh2, const float* __restrict__ bh3,
    const float* __restrict__ aw1, const float* __restrict__ cw1,
    const float* __restrict__ w3s,
    unsigned short* __restrict__ wsW, unsigned short* __restrict__ wsH,
    unsigned short* __restrict__ wsW3, float* __restrict__ wsB) {
  const int y = blockIdx.y;
  const int i = blockIdx.x * NT + threadIdx.x;
  if (y < 8) {
    if (i >= 12288) return;
    const float* src = (y == 0) ? W0 : (y == 1) ? W1 : (y == 2) ? W2 : (y == 3) ? W3
                     : (y == 4) ? W4 : (y == 5) ? W5 : (y == 6) ? W6 : W7;
    wsW[(y >> 1) * 24576 + (y & 1) * 12288 + i] = f2b(src[i]);
  } else if (y == 8) {
    if (i < 4096) wsH[i] = f2b(aw1[i]);
  } else if (y == 9) {
    if (i < 4096) wsH[4096 + i] = f2b(cw1[i]);
  } else if (y == 10) {
    if (i < 8192) wsW3[i] = f2b(w3s[i]);
  } else {
    const int c = y - 11;
    if (i < 256) {
      const float* bi = (c == 0) ? bi0 : (c == 1) ? bi1 : (c == 2) ? bi2 : bi3;
      const float* bh = (c == 0) ? bh0 : (c == 1) ? bh1 : (c == 2) ? bh2 : bh3;
      const int j = i & 63, g = i >> 6;
      float v = (g == 0) ? bi[j] + bh[j]
              : (g == 1) ? bi[64 + j] + bh[64 + j]
              : (g == 2) ? bi[128 + j] : bh[128 + j];
      wsB[c * 256 + i] = v;
    }
  }
}

// ---------------- conv1 (2x2, 3->16) + ReLU + maxpool2, split by ph ----------------
__global__ __launch_bounds__(NT) void k_conv1(const float* __restrict__ obs,
                                              const float* __restrict__ w1,
                                              const float* __restrict__ b1,
                                              float* __restrict__ pooled_t) {
  const int ph = blockIdx.x >> 8;
  const int s = ((blockIdx.x & 255) << 8) + threadIdx.x;
  const float* o = obs + (size_t)s * 147;
  float r[3][21];
#pragma unroll
  for (int rr = 0; rr < 3; ++rr) {
    const float* orow = o + (2 * ph + rr) * 21;
#pragma unroll
    for (int i = 0; i < 21; ++i) r[rr][i] = orow[i];
  }
#pragma unroll 1
  for (int oc = 0; oc < 16; ++oc) {
    float wv[12];
#pragma unroll
    for (int i = 0; i < 12; ++i) wv[i] = w1[oc * 12 + i];
    const float bias = b1[oc];
#pragma unroll
    for (int pw = 0; pw < 3; ++pw) {
      float m = 0.0f;
#pragma unroll
      for (int dh = 0; dh < 2; ++dh)
#pragma unroll
        for (int dw = 0; dw < 2; ++dw) {
          float acc = bias;
#pragma unroll
          for (int kh = 0; kh < 2; ++kh)
#pragma unroll
            for (int kw = 0; kw < 2; ++kw)
#pragma unroll
              for (int c = 0; c < 3; ++c)
                acc += r[dh + kh][(2 * pw + dw + kw) * 3 + c] * wv[c * 4 + kh * 2 + kw];
          m = fmaxf(m, fmaxf(acc, 0.0f));
        }
      pooled_t[(size_t)(oc * 9 + ph * 3 + pw) * BATCH + s] = m;
    }
  }
}

// ---------------- conv2 (2x2, 16->32) + ReLU -> bf16 [B][128] row-major ----------------
__global__ __launch_bounds__(NT) void k_conv2(const float* __restrict__ pooled_t,
                                              const float* __restrict__ w2,
                                              const float* __restrict__ b2,
                                              unsigned short* __restrict__ c2b) {
  const int g = blockIdx.x >> 8;           // oc half
  const int s = ((blockIdx.x & 255) << 8) + threadIdx.x;
  const int ocb = 16 * g;
  float acc[16][4];
#pragma unroll
  for (int u = 0; u < 16; ++u) {
    const float bb = b2[ocb + u];
    acc[u][0] = bb; acc[u][1] = bb; acc[u][2] = bb; acc[u][3] = bb;
  }
#pragma unroll 1
  for (int ic = 0; ic < 16; ++ic) {
    float p9[9];
#pragma unroll
    for (int p = 0; p < 9; ++p) p9[p] = pooled_t[(size_t)(ic * 9 + p) * BATCH + s];
#pragma unroll
    for (int u = 0; u < 16; ++u) {
      float w[4];
#pragma unroll
      for (int i = 0; i < 4; ++i) w[i] = w2[((ocb + u) * 16 + ic) * 4 + i];
#pragma unroll
      for (int oh = 0; oh < 2; ++oh)
#pragma unroll
        for (int ow = 0; ow < 2; ++ow)
          acc[u][oh * 2 + ow] += p9[(oh + 0) * 3 + (ow + 0)] * w[0] +
                                 p9[(oh + 0) * 3 + (ow + 1)] * w[1] +
                                 p9[(oh + 1) * 3 + (ow + 0)] * w[2] +
                                 p9[(oh + 1) * 3 + (ow + 1)] * w[3];
    }
  }
  unsigned short ob[64];
#pragma unroll
  for (int u = 0; u < 16; ++u)
#pragma unroll
    for (int p = 0; p < 4; ++p) ob[u * 4 + p] = f2b(fmaxf(acc[u][p], 0.0f));
#pragma unroll
  for (int i = 0; i < 8; ++i)
    *(u16x8*)(c2b + (size_t)s * 128 + ocb * 4 + 8 * i) = *(const u16x8*)(ob + 8 * i);
}

// ---------------- fused: conv3-GEMM + 4 GRU cells + heads ----------------
// wave = 32 samples (2 M-tiles); x handed between stages via per-wave LDS rows.
#define XSTR 88   // LDS row stride (u16): 176B = 16B-aligned, 2-way max bank alias
__global__ __launch_bounds__(NT) void k_gru(
    const unsigned short* __restrict__ c2b,
    const float* __restrict__ memF,
    const unsigned short* __restrict__ wsW,
    const unsigned short* __restrict__ wsW3,
    const float* __restrict__ wsB,
    const unsigned short* __restrict__ wsH,
    const float* __restrict__ b3,
    const float* __restrict__ ab1, const float* __restrict__ cb1,
    const float* __restrict__ aw2, const float* __restrict__ ab2,
    const float* __restrict__ cw2, const float* __restrict__ cb2,
    float* __restrict__ out) {
  __shared__ unsigned short xls[128 * XSTR];
  const int lane = threadIdx.x & 63;
  const int wave = threadIdx.x >> 6;
  const int r16 = lane & 15;
  const int kg = lane >> 4;
  const int wbase = wave * 32;                  // local sample base
  const int m_base = blockIdx.x * 128 + wbase;  // global sample base
  float* outMem = out + (size_t)4 * BATCH;

  // ---- stage 0: x = relu(c2 @ w3^T + b3) -> xls ----
  {
    bf16x8 a0[4], a1[4];
    const unsigned short* ap0 = c2b + (size_t)(m_base + r16) * 128 + kg * 8;
    const unsigned short* ap1 = c2b + (size_t)(m_base + 16 + r16) * 128 + kg * 8;
#pragma unroll
    for (int f = 0; f < 4; ++f) {
      a0[f] = *(const bf16x8*)(ap0 + f * 32);
      a1[f] = *(const bf16x8*)(ap1 + f * 32);
    }
#pragma unroll
    for (int n = 0; n < 4; ++n) {
      const float bias = b3[n * 16 + r16];
      const unsigned short* bp = wsW3 + (size_t)(n * 16 + r16) * 128 + kg * 8;
      bf16x8 b[4];
#pragma unroll
      for (int f = 0; f < 4; ++f) b[f] = *(const bf16x8*)(bp + f * 32);
      f32x4 q0 = (f32x4)(0.0f), q1 = (f32x4)(0.0f);
#pragma unroll
      for (int f = 0; f < 4; ++f) {
        q0 = MFMA(a0[f], b[f], q0, 0, 0, 0);
        q1 = MFMA(a1[f], b[f], q1, 0, 0, 0);
      }
#pragma unroll
      for (int q = 0; q < 4; ++q) {
        xls[(wbase + kg * 4 + q) * XSTR + n * 16 + r16] = f2b(fmaxf(q0[q] + bias, 0.0f));
        xls[(wbase + 16 + kg * 4 + q) * XSTR + n * 16 + r16] = f2b(fmaxf(q1[q] + bias, 0.0f));
      }
    }
  }

  // ---- stage 1: 4 GRU cells ----
  bf16x8 ax[2][2];
#pragma unroll 1
  for (int c = 0; c < 4; ++c) {
#pragma unroll
    for (int Mt = 0; Mt < 2; ++Mt) {
      const unsigned short* xp = xls + (wbase + Mt * 16 + r16) * XSTR + kg * 8;
      ax[Mt][0] = *(const bf16x8*)(xp);
      ax[Mt][1] = *(const bf16x8*)(xp + 32);
    }
    const unsigned short* Wc = wsW + c * 24576;
    const float* bcp = wsB + c * 256;
    const int co = c * 64;
    bf16x8 ah[2][2];
#pragma unroll
    for (int Mt = 0; Mt < 2; ++Mt) {
      const float* hp = memF + (size_t)(m_base + Mt * 16 + r16) * 256 + co + kg * 8;
#pragma unroll
      for (int sl = 0; sl < 2; ++sl) {
        union { unsigned short u[8]; bf16x8 v; } t;
#pragma unroll
        for (int e = 0; e < 8; ++e) t.u[e] = f2b(hp[sl * 32 + e]);
        ah[Mt][sl] = t.v;
      }
    }
#pragma unroll 1
    for (int jt = 0; jt < 4; ++jt) {
      const unsigned short* w0 = Wc + (size_t)(jt * 16 + r16) * 64 + kg * 8;
      bf16x8 br0 = *(const bf16x8*)(w0);
      bf16x8 br1 = *(const bf16x8*)(w0 + 32);
      bf16x8 bz0 = *(const bf16x8*)(w0 + 64 * 64);
      bf16x8 bz1 = *(const bf16x8*)(w0 + 64 * 64 + 32);
      bf16x8 bn0 = *(const bf16x8*)(w0 + 128 * 64);
      bf16x8 bn1 = *(const bf16x8*)(w0 + 128 * 64 + 32);
      bf16x8 cr0 = *(const bf16x8*)(w0 + 192 * 64);
      bf16x8 cr1 = *(const bf16x8*)(w0 + 192 * 64 + 32);
      bf16x8 cz0 = *(const bf16x8*)(w0 + 256 * 64);
      bf16x8 cz1 = *(const bf16x8*)(w0 + 256 * 64 + 32);
      bf16x8 cn0 = *(const bf16x8*)(w0 + 320 * 64);
      bf16x8 cn1 = *(const bf16x8*)(w0 + 320 * 64 + 32);
      f32x4 sr[2], sz[2], sn[2], tr[2], tz[2], tn[2];
#pragma unroll
      for (int Mt = 0; Mt < 2; ++Mt) {
        sr[Mt] = (f32x4)(0.0f); sz[Mt] = (f32x4)(0.0f); sn[Mt] = (f32x4)(0.0f);
        tr[Mt] = (f32x4)(0.0f); tz[Mt] = (f32x4)(0.0f); tn[Mt] = (f32x4)(0.0f);
      }
#pragma unroll
      for (int Mt = 0; Mt < 2; ++Mt) {
        sr[Mt] = MFMA(ax[Mt][0], br0, sr[Mt], 0, 0, 0);
        sr[Mt] = MFMA(ax[Mt][1], br1, sr[Mt], 0, 0, 0);
        sz[Mt] = MFMA(ax[Mt][0], bz0, sz[Mt], 0, 0, 0);
        sz[Mt] = MFMA(ax[Mt][1], bz1, sz[Mt], 0, 0, 0);
        sn[Mt] = MFMA(ax[Mt][0], bn0, sn[Mt], 0, 0, 0);
        sn[Mt] = MFMA(ax[Mt][1], bn1, sn[Mt], 0, 0, 0);
        tr[Mt] = MFMA(ah[Mt][0], cr0, tr[Mt], 0, 0, 0);
        tr[Mt] = MFMA(ah[Mt][1], cr1, tr[Mt], 0, 0, 0);
        tz[Mt] = MFMA(ah[Mt][0], cz0, tz[Mt], 0, 0, 0);
        tz[Mt] = MFMA(ah[Mt][1], cz1, tz[Mt], 0, 0, 0);
        tn[Mt] = MFMA(ah[Mt][0], cn0, tn[Mt], 0, 0, 0);
        tn[Mt] = MFMA(ah[Mt][1], cn1, tn[Mt], 0, 0, 0);
      }
      const float rb = bcp[jt * 16 + r16];
      const float zb = bcp[64 + jt * 16 + r16];
      const float inb = bcp[128 + jt * 16 + r16];
      const float hnb = bcp[192 + jt * 16 + r16];
#pragma unroll
      for (int Mt = 0; Mt < 2; ++Mt)
#pragma unroll
        for (int q = 0; q < 4; ++q) {
          const int sq = m_base + Mt * 16 + kg * 4 + q;
          const float rg = sigmoidf_(sr[Mt][q] + tr[Mt][q] + rb);
          const float zg = sigmoidf_(sz[Mt][q] + tz[Mt][q] + zb);
          const float ng = tanhf_((sn[Mt][q] + inb) + rg * (tn[Mt][q] + hnb));
          const float ho = memF[(size_t)sq * 256 + co + jt * 16 + r16];
          const float nh = (1.0f - zg) * ng + zg * ho;
          outMem[(size_t)sq * 256 + co + jt * 16 + r16] = nh;
          xls[(wbase + Mt * 16 + kg * 4 + q) * XSTR + jt * 16 + r16] = f2b(nh);
        }
    }
  }

  // ---- stage 2: heads ----
#pragma unroll
  for (int Mt = 0; Mt < 2; ++Mt) {
    const unsigned short* xp = xls + (wbase + Mt * 16 + r16) * XSTR + kg * 8;
    ax[Mt][0] = *(const bf16x8*)(xp);
    ax[Mt][1] = *(const bf16x8*)(xp + 32);
  }
  f32x4 ha[2][8];
#pragma unroll
  for (int Mt = 0; Mt < 2; ++Mt)
#pragma unroll
    for (int n = 0; n < 8; ++n) ha[Mt][n] = (f32x4)(0.0f);
#pragma unroll
  for (int n = 0; n < 8; ++n) {
    const unsigned short* wp = wsH + (size_t)(n * 16 + r16) * 64 + kg * 8;
    bf16x8 b0 = *(const bf16x8*)(wp);
    bf16x8 b1 = *(const bf16x8*)(wp + 32);
#pragma unroll
    for (int Mt = 0; Mt < 2; ++Mt) {
      ha[Mt][n] = MFMA(ax[Mt][0], b0, ha[Mt][n], 0, 0, 0);
      ha[Mt][n] = MFMA(ax[Mt][1], b1, ha[Mt][n], 0, 0, 0);
    }
  }
  float w2a0[4], w2a1[4], w2a2[4], w2cc[4], bav[4], bcv[4];
#pragma unroll
  for (int t = 0; t < 4; ++t) {
    const int j = 16 * t + r16;
    w2a0[t] = aw2[j]; w2a1[t] = aw2[64 + j]; w2a2[t] = aw2[128 + j];
    w2cc[t] = cw2[j]; bav[t] = ab1[j]; bcv[t] = cb1[j];
  }
  const float b20 = ab2[0], b21 = ab2[1], b22 = ab2[2], b2c = cb2[0];
#pragma unroll
  for (int Mt = 0; Mt < 2; ++Mt)
#pragma unroll
    for (int q = 0; q < 4; ++q) {
      float l0 = 0.0f, l1 = 0.0f, l2 = 0.0f, vv = 0.0f;
#pragma unroll
      for (int t = 0; t < 4; ++t) {
        const float av = fmaxf(ha[Mt][t][q] + bav[t], 0.0f);
        const float cv = fmaxf(ha[Mt][t + 4][q] + bcv[t], 0.0f);
        l0 += av * w2a0[t]; l1 += av * w2a1[t]; l2 += av * w2a2[t];
        vv += cv * w2cc[t];
      }
#pragma unroll
      for (int m = 1; m < 16; m <<= 1) {
        l0 += __shfl_xor(l0, m); l1 += __shfl_xor(l1, m);
        l2 += __shfl_xor(l2, m); vv += __shfl_xor(vv, m);
      }
      if (r16 == 0) {
        const int sq = m_base + Mt * 16 + kg * 4 + q;
        const float g0 = l0 + b20, g1 = l1 + b21, g2 = l2 + b22;
        const float mx = fmaxf(g0, fmaxf(g1, g2));
        const float lse = mx + __logf(__expf(g0 - mx) + __expf(g1 - mx) + __expf(g2 - mx));
        out[(size_t)sq * 3 + 0] = g0 - lse;
        out[(size_t)sq * 3 + 1] = g1 - lse;
        out[(size_t)sq * 3 + 2] = g2 - lse;
        out[(size_t)3 * BATCH + sq] = vv + b2c;
      }
    }
}

extern "C" void kernel_launch(void* const* d_in, const int* in_sizes, int n_in,
                              void* d_out, int out_size, void* d_ws, size_t ws_size,
                              hipStream_t stream) {
  (void)in_sizes; (void)n_in; (void)out_size; (void)ws_size;
  const float* obs = (const float*)d_in[0];
  const float* mem = (const float*)d_in[1];
  const float* w1 = (const float*)d_in[2];
  const float* b1 = (const float*)d_in[3];
  const float* w2 = (const float*)d_in[4];
  const float* b2 = (const float*)d_in[5];
  const float* w3 = (const float*)d_in[6];
  const float* b3 = (const float*)d_in[7];
  const float* gw[16];
  for (int i = 0; i < 16; ++i) gw[i] = (const float*)d_in[8 + i];
  const float* aw1 = (const float*)d_in[24];
  const float* ab1 = (const float*)d_in[25];
  const float* aw2 = (const float*)d_in[26];
  const float* ab2 = (const float*)d_in[27];
  const float* cw1 = (const float*)d_in[28];
  const float* cb1 = (const float*)d_in[29];
  const float* cw2 = (const float*)d_in[30];
  const float* cb2 = (const float*)d_in[31];

  float* out = (float*)d_out;

  char* w = (char*)d_ws;
  float* pooled_t = (float*)w;                                      // 144*B f32
  unsigned short* c2b = (unsigned short*)(w + (size_t)144 * BATCH * 4);  // [B][128] bf16
  unsigned short* wsW = c2b + (size_t)128 * BATCH;                  // 4*384*64
  unsigned short* wsH = wsW + 98304;                                // 128*64
  unsigned short* wsW3 = wsH + 8192;                                // 64*128
  float* wsB = (float*)(wsW3 + 8192);                               // 4*256 f32

  const dim3 blk(NT);
  hipLaunchKernelGGL(k_prep, dim3(48, 15), blk, 0, stream,
                     gw[0], gw[1], gw[4], gw[5], gw[8], gw[9], gw[12], gw[13],
                     gw[2], gw[6], gw[10], gw[14],
                     gw[3], gw[7], gw[11], gw[15],
                     aw1, cw1, w3, wsW, wsH, wsW3, wsB);
  hipLaunchKernelGGL(k_conv1, dim3(768), blk, 0, stream, obs, w1, b1, pooled_t);
  hipLaunchKernelGGL(k_conv2, dim3(512), blk, 0, stream, pooled_t, w2, b2, c2b);
  hipLaunchKernelGGL(k_gru, dim3(BATCH / 128), blk, 0, stream,
                     c2b, mem, wsW, wsW3, wsB, wsH, b3,
                     ab1, cb1, aw2, ab2, cw2, cb2, out);
}